// Round 6
// baseline (10062.126 us; speedup 1.0000x reference)
//
#include <hip/hip_runtime.h>
#include <math.h>

#define BB 64
#define SS 512
#define EE 512
#define HH 1024
#define NWG 64

typedef __attribute__((ext_vector_type(8))) short bf16x8;
typedef __attribute__((ext_vector_type(4))) float f32x4;
typedef __attribute__((ext_vector_type(2))) unsigned int u32x2;
typedef unsigned short ushort_t;

#define DOT4(acc, u, v) acc += (u).x*(v).x + (u).y*(v).y + (u).z*(v).z + (u).w*(v).w

__device__ __forceinline__ unsigned short bf16_hi(float x) {
    union { float f; unsigned u; } c; c.f = x;
    unsigned r = c.u + 0x7fffu + ((c.u >> 16) & 1u);   // RNE
    return (unsigned short)(r >> 16);
}
__device__ __forceinline__ float bf16_f(unsigned short h) {
    union { unsigned u; float f; } c; c.u = ((unsigned)h) << 16;
    return c.f;
}

// sc1 = agent-coherent (bypass stale per-XCD L2). 16B-granule loads.
#define A_LD(dst, addr) \
    asm volatile("global_load_dwordx4 %0, %1, off sc1" : "=v"(dst) : "v"(addr))
#define FLAG_LD(dst, addr) \
    asm volatile("global_load_dwordx2 %0, %1, off sc1" : "=v"(dst) : "v"(addr))
#define ST_H(addr, val) \
    asm volatile("global_store_short %0, %1, off sc1" :: "v"(addr), "v"(val) : "memory")
#define ST_D(addr, val) \
    asm volatile("global_store_dword %0, %1, off sc1" :: "v"(addr), "v"(val) : "memory")
#define WAITV() do { asm volatile("s_waitcnt vmcnt(0)" ::: "memory"); \
                     __builtin_amdgcn_sched_barrier(0); } while (0)

// ---- pack Wf|Wh (cols interleaved: jcat=2j -> Wf col j, 2j+1 -> Wh col j)
// into MFMA B-fragment order, split bf16 hi/lo (round-4-verified layout):
// Wp[((n*32+ks)*64+l)*8+i] = Wcat[k=ks*32+(l>>4)*8+i][jcat=16n+(l&15)]
__global__ __launch_bounds__(64) void packw_kernel(
    const float* __restrict__ Wf, const float* __restrict__ Wh,
    ushort_t* __restrict__ Wph, ushort_t* __restrict__ Wpl)
{
    int n = blockIdx.x, ks = blockIdx.y, l = threadIdx.x;
    int jcat  = 16*n + (l & 15);
    int kbase = ks*32 + ((l >> 4) << 3);
    const float* src = ((jcat & 1) ? Wh : Wf) + (size_t)(jcat >> 1)*HH + kbase;
    size_t o = ((size_t)(n*32 + ks)*64 + l) * 8;
    #pragma unroll
    for (int i = 0; i < 8; ++i) {
        float x = src[i];
        unsigned short hi = bf16_hi(x);
        Wph[o+i] = hi;
        Wpl[o+i] = bf16_hi(x - bf16_f(hi));
    }
}

// ---- input gate (hoisted, fp32): INP[t][b][j] = relu(emb[x[b][t]] . Wi[j] + bi[j])
__global__ __launch_bounds__(512) void gemm1_kernel(
    const int* __restrict__ x, const float* __restrict__ emb,
    const float* __restrict__ Wi, const float* __restrict__ bi,
    float* __restrict__ INP)
{
    int t    = blockIdx.y;
    int lane = threadIdx.x & 63;
    int wave = __builtin_amdgcn_readfirstlane(threadIdx.x >> 6);
    int j4   = blockIdx.x * 8 + wave;

    int row = x[lane * SS + t];
    const float4* e  = reinterpret_cast<const float4*>(emb + (size_t)row * EE);
    const float4* w0 = reinterpret_cast<const float4*>(Wi + (size_t)(j4*4+0) * EE);
    const float4* w1 = reinterpret_cast<const float4*>(Wi + (size_t)(j4*4+1) * EE);
    const float4* w2 = reinterpret_cast<const float4*>(Wi + (size_t)(j4*4+2) * EE);
    const float4* w3 = reinterpret_cast<const float4*>(Wi + (size_t)(j4*4+3) * EE);

    float a0 = 0.f, a1 = 0.f, a2 = 0.f, a3 = 0.f;
    #pragma unroll 8
    for (int k4 = 0; k4 < EE/4; ++k4) {
        float4 ev = e[k4];
        float4 w;
        w = w0[k4]; DOT4(a0, ev, w);
        w = w1[k4]; DOT4(a1, ev, w);
        w = w2[k4]; DOT4(a2, ev, w);
        w = w3[k4]; DOT4(a3, ev, w);
    }
    float4 bv = *reinterpret_cast<const float4*>(bi + j4*4);
    float4 r;
    r.x = fmaxf(a0 + bv.x, 0.f);
    r.y = fmaxf(a1 + bv.y, 0.f);
    r.z = fmaxf(a2 + bv.z, 0.f);
    r.w = fmaxf(a3 + bv.w, 0.f);
    *reinterpret_cast<float4*>(INP + ((size_t)t*BB + lane)*HH + j4*4) = r;
}

// ---- persistent recurrence: 64 WGs x 16 waves; WG w owns h-outputs [16w,16w+16)
// (gate cols [32w,32w+32)). Weights in LDS; h exchanged via sc1; per-producer flags.
__global__ __launch_bounds__(1024) void seq_kernel(
    const float* __restrict__ INP,
    const ushort_t* __restrict__ Wph, const ushort_t* __restrict__ Wpl,
    const float* __restrict__ bfv, const float* __restrict__ bhv,
    const int* __restrict__ lengths,
    ushort_t* __restrict__ hhi0, ushort_t* __restrict__ hlo0,
    ushort_t* __restrict__ hhi1, ushort_t* __restrict__ hlo1,
    float* __restrict__ hselT, unsigned* __restrict__ flags)
{
    // LDS: Bh [2][32][64][8]bf16 = 64KB | Bl 64KB | red 24KB  = 152KB
    __shared__ __align__(16) char smem[155648];

    const int tid = threadIdx.x;
    const int l   = tid & 63;
    const int w16 = __builtin_amdgcn_readfirstlane(tid >> 6);   // 0..15
    const int m   = w16 & 3;       // M-tile (rows 16m..16m+16)
    const int kk  = w16 >> 2;      // K-split class 0..3
    const int wg  = blockIdx.x;

    // stage this WG's weight slice (frag order) into LDS
    {
        const float4* gh = (const float4*)(Wph + (size_t)wg * 32768);
        const float4* gl = (const float4*)(Wpl + (size_t)wg * 32768);
        float4* lh = (float4*)smem;
        float4* ll = (float4*)(smem + 65536);
        for (int i = tid; i < 4096; i += 1024) { lh[i] = gh[i]; ll[i] = gl[i]; }
    }
    f32x4* red = (f32x4*)(smem + 131072);

    const int  u   = (l & 15) >> 1;
    const bool isf = !(l & 1);
    const int  j0  = 16*wg + u, j1 = 16*wg + 8 + u;
    const float bf0 = bfv[j0], bh0 = bhv[j0], bf1 = bfv[j1], bh1 = bhv[j1];
    int brow[4], blen[4];
    #pragma unroll
    for (int r = 0; r < 4; ++r) {
        brow[r] = 16*m + ((l >> 4) << 2) + r;
        blen[r] = lengths[brow[r]];
    }
    const int arow = 16*m + (l & 15);
    __syncthreads();

    for (int t = 0; t < SS; ++t) {
        const ushort_t* hi_in  = (t & 1) ? hhi1 : hhi0;
        const ushort_t* lo_in  = (t & 1) ? hlo1 : hlo0;
        ushort_t*       hi_out = (t & 1) ? hhi0 : hhi1;
        ushort_t*       lo_out = (t & 1) ? hlo0 : hlo1;

        // -- 1. burst-load the 16 flags this wave depends on (8 producer pairs)
        u32x2 fl[8];
        #pragma unroll
        for (int q8 = 0; q8 < 8; ++q8)
            FLAG_LD(fl[q8], flags + 2*(kk + 4*q8));
        WAITV();
        #pragma unroll
        for (int q8 = 0; q8 < 8; ++q8) {
            if (fl[q8].x < (unsigned)t || fl[q8].y < (unsigned)t) {
                const unsigned* fp = flags + 2*(kk + 4*q8);
                unsigned guard = 0;
                u32x2 ff;
                do {
                    __builtin_amdgcn_s_sleep(2);
                    FLAG_LD(ff, fp);
                    asm volatile("s_waitcnt vmcnt(0)" ::: "memory");
                } while ((ff.x < (unsigned)t || ff.y < (unsigned)t) && ++guard < (1u<<20));
            }
        }

        // -- 2. epilogue waves prefetch this step's INP (plain cached loads)
        float ivp[2][4];
        if (kk == 0) {
            #pragma unroll
            for (int c = 0; c < 2; ++c)
                #pragma unroll
                for (int r = 0; r < 4; ++r) {
                    const float* ia = INP + ((size_t)t*BB + brow[r])*HH + (c ? j1 : j0);
                    asm volatile("global_load_dword %0, %1, off" : "=v"(ivp[c][r]) : "v"(ia));
                }
        }

        // -- 3. MFMA over this wave's 8 k-steps, two bursts of 4
        f32x4 acc0 = {0.f,0.f,0.f,0.f}, acc1 = {0.f,0.f,0.f,0.f};
        #pragma unroll
        for (int half = 0; half < 2; ++half) {
            bf16x8 ah[4], al[4];
            #pragma unroll
            for (int q = 0; q < 4; ++q) {
                int s = kk + 4*(half*4 + q);
                const ushort_t* aa = hi_in + (size_t)arow*HH + s*32 + ((l >> 4) << 3);
                const ushort_t* bb = lo_in + (size_t)arow*HH + s*32 + ((l >> 4) << 3);
                A_LD(ah[q], aa);
                A_LD(al[q], bb);
            }
            WAITV();
            #pragma unroll
            for (int q = 0; q < 4; ++q) {
                int s = kk + 4*(half*4 + q);
                bf16x8 b0h = *(const bf16x8*)(smem +           (((0*32 + s)*64 + l) << 4));
                bf16x8 b1h = *(const bf16x8*)(smem +           (((1*32 + s)*64 + l) << 4));
                bf16x8 b0l = *(const bf16x8*)(smem + 65536 +   (((0*32 + s)*64 + l) << 4));
                bf16x8 b1l = *(const bf16x8*)(smem + 65536 +   (((1*32 + s)*64 + l) << 4));
                acc0 = __builtin_amdgcn_mfma_f32_16x16x32_bf16(ah[q], b0h, acc0, 0, 0, 0);
                acc0 = __builtin_amdgcn_mfma_f32_16x16x32_bf16(ah[q], b0l, acc0, 0, 0, 0);
                acc0 = __builtin_amdgcn_mfma_f32_16x16x32_bf16(al[q], b0h, acc0, 0, 0, 0);
                acc1 = __builtin_amdgcn_mfma_f32_16x16x32_bf16(ah[q], b1h, acc1, 0, 0, 0);
                acc1 = __builtin_amdgcn_mfma_f32_16x16x32_bf16(ah[q], b1l, acc1, 0, 0, 0);
                acc1 = __builtin_amdgcn_mfma_f32_16x16x32_bf16(al[q], b1h, acc1, 0, 0, 0);
            }
        }

        // -- 4. K-split reduce
        if (kk) {
            red[((kk-1)*8 + m*2 + 0)*64 + l] = acc0;
            red[((kk-1)*8 + m*2 + 1)*64 + l] = acc1;
        }
        __syncthreads();

        // -- 5. epilogue (kk==0 waves): reduce, nonlinearity, publish h
        if (kk == 0) {
            #pragma unroll
            for (int q = 0; q < 3; ++q) {
                acc0 += red[(q*8 + m*2 + 0)*64 + l];
                acc1 += red[(q*8 + m*2 + 1)*64 + l];
            }
            #pragma unroll
            for (int c = 0; c < 2; ++c) {
                f32x4 a = c ? acc1 : acc0;
                const int   jj  = c ? j1  : j0;
                const float bfc = c ? bf1 : bf0;
                const float bhc = c ? bh1 : bh0;
                #pragma unroll
                for (int r = 0; r < 4; ++r) {
                    float self  = a[r];
                    float other = __shfl_xor(self, 1);
                    float sf = (isf ? self  : other) + bfc;
                    float sh = (isf ? other : self ) + bhc;
                    float hn = 0.f;
                    if (isf) hn = 1.f/(1.f + expf(-sf)) + tanhf(sh) * ivp[c][r];
                    float hno = __shfl_xor(hn, 1);
                    if (!isf) hn = hno;
                    unsigned short hb = bf16_hi(hn);
                    int b = brow[r];
                    if (isf) {
                        ST_H(hi_out + (size_t)b*HH + jj, (unsigned)hb);
                        if (t == blen[r] - 1) hselT[(size_t)jj*BB + b] = hn;
                    } else {
                        ST_H(lo_out + (size_t)b*HH + jj,
                             (unsigned)bf16_hi(hn - bf16_f(hb)));
                    }
                }
            }
            asm volatile("s_waitcnt vmcnt(0)" ::: "memory");
        }
        __syncthreads();

        // -- 6. publish completion of step t
        if (tid == 0) ST_D(flags + wg, (unsigned)(t + 1));
    }
}

// ---- output projection: lin[b][j] = hsel[b] . Wo[j] + bo[j]; hselT is [k][b]
__global__ __launch_bounds__(1024) void outproj_kernel(
    const float* __restrict__ hselT, const float* __restrict__ Wo,
    const float* __restrict__ bov, float* __restrict__ lin)
{
    __shared__ float pf[16][4][64];
    const int tid  = threadIdx.x;
    const int lane = tid & 63;
    const int kq   = __builtin_amdgcn_readfirstlane(tid >> 6);
    const int jg   = blockIdx.x;

    const float* w0 = Wo + (size_t)(jg*4+0)*HH + kq*64;
    const float* w1 = Wo + (size_t)(jg*4+1)*HH + kq*64;
    const float* w2 = Wo + (size_t)(jg*4+2)*HH + kq*64;
    const float* w3 = Wo + (size_t)(jg*4+3)*HH + kq*64;
    const float* hb = hselT + (size_t)kq*64*64 + lane;

    float a0=0.f, a1=0.f, a2=0.f, a3=0.f;
    #pragma unroll 8
    for (int kkk = 0; kkk < 64; ++kkk) {
        float hv = hb[(size_t)kkk*64];
        a0 = fmaf(hv, w0[kkk], a0);
        a1 = fmaf(hv, w1[kkk], a1);
        a2 = fmaf(hv, w2[kkk], a2);
        a3 = fmaf(hv, w3[kkk], a3);
    }
    pf[kq][0][lane]=a0; pf[kq][1][lane]=a1; pf[kq][2][lane]=a2; pf[kq][3][lane]=a3;
    __syncthreads();

    const int fc = tid >> 6, fb = tid & 63;
    if (tid < 256) {
        float s = bov[jg*4 + fc];
        #pragma unroll
        for (int q = 0; q < 16; ++q) s += pf[q][fc][fb];
        lin[((size_t)jg*64 + fb)*4 + fc] = s;
    }
}

__global__ __launch_bounds__(64) void final_kernel(
    const float4* __restrict__ lin, const float* __restrict__ Wlin,
    const float* __restrict__ blin, float* __restrict__ out)
{
    int b = threadIdx.x;
    float l0 = blin[0], l1 = blin[1];
    const float4* w0 = reinterpret_cast<const float4*>(Wlin);
    const float4* w1 = reinterpret_cast<const float4*>(Wlin) + 256;
    #pragma unroll 4
    for (int j4 = 0; j4 < 256; ++j4) {
        float4 v = lin[j4*64 + b];
        float4 wa = w0[j4], wb = w1[j4];
        DOT4(l0, v, wa);
        DOT4(l1, v, wb);
    }
    float m   = fmaxf(l0, l1);
    float lse = m + logf(expf(l0 - m) + expf(l1 - m));
    out[b*2 + 0] = l0 - lse;
    out[b*2 + 1] = l1 - lse;
}

extern "C" void kernel_launch(void* const* d_in, const int* in_sizes, int n_in,
                              void* d_out, int out_size, void* d_ws, size_t ws_size,
                              hipStream_t stream) {
    (void)in_sizes; (void)n_in; (void)out_size; (void)ws_size;
    const int*   x       = (const int*)  d_in[0];
    const int*   lengths = (const int*)  d_in[1];
    const float* emb     = (const float*)d_in[2];
    const float* Wi      = (const float*)d_in[3];
    const float* bi      = (const float*)d_in[4];
    const float* Wf      = (const float*)d_in[5];
    const float* bf      = (const float*)d_in[6];
    const float* Wh      = (const float*)d_in[7];
    const float* bh      = (const float*)d_in[8];
    const float* Wo      = (const float*)d_in[9];
    const float* bo      = (const float*)d_in[10];
    const float* Wlin    = (const float*)d_in[11];
    const float* blin    = (const float*)d_in[12];
    float* out = (float*)d_out;

    char* ws = (char*)d_ws;
    const size_t INP_BYTES = (size_t)SS * BB * HH * sizeof(float);     // 128 MiB
    float*     INP   = (float*)ws;
    ushort_t*  Wph   = (ushort_t*)(ws + INP_BYTES);                    // 4 MiB
    ushort_t*  Wpl   = Wph + (size_t)2*1024*1024;                      // 4 MiB
    ushort_t*  hhi0  = Wpl + (size_t)2*1024*1024;                      // 128 KiB each
    ushort_t*  hlo0  = hhi0 + BB*HH;
    ushort_t*  hhi1  = hlo0 + BB*HH;
    ushort_t*  hlo1  = hhi1 + BB*HH;
    float*     hselT = (float*)(hlo1 + BB*HH);                         // 256 KiB
    float*     lin   = hselT + BB*HH;                                  // 256 KiB
    unsigned*  flags = (unsigned*)(lin + BB*HH);

    hipMemsetAsync(hhi0, 0, 2*BB*HH*sizeof(ushort_t), stream);         // h(0)=0 hi+lo
    hipMemsetAsync(flags, 0, NWG*sizeof(unsigned), stream);

    packw_kernel<<<dim3(128, 32), 64, 0, stream>>>(Wf, Wh, Wph, Wpl);
    gemm1_kernel<<<dim3(32, 512), 512, 0, stream>>>(x, emb, Wi, bi, INP);

    void* args[] = {&INP, &Wph, &Wpl, &bf, &bh, &lengths,
                    &hhi0, &hlo0, &hhi1, &hlo1, &hselT, &flags};
    hipLaunchCooperativeKernel((const void*)seq_kernel, dim3(NWG), dim3(1024),
                               args, 0, stream);

    outproj_kernel<<<256, 1024, 0, stream>>>(hselT, Wo, bo, lin);
    final_kernel<<<1, 64, 0, stream>>>((const float4*)lin, Wlin, blin, out);
}